// Round 6
// baseline (477.580 us; speedup 1.0000x reference)
//
#include <hip/hip_runtime.h>

// ---------------------------------------------------------------------------
// AttnBlock: GroupNorm -> q,k,v 1x1 conv -> softmax(QK^T/sqrt(c)) V -> out
// conv -> residual.  b=4, c=512, h=w=64 (n=4096), 32 groups.
// R6: gemm_core LDS retiled to FRAGMENT-MAJOR 1KB blocks (each ds_read_b128
//     is lds+lane*16 -> stride-1, conflict-free; global_load_lds lane->elem
//     mapping permuted to match). gn_stats split 128->512 blocks with
//     partial sums folded into gn_apply.
// ---------------------------------------------------------------------------

typedef __attribute__((ext_vector_type(8))) short bf16x8;   // 8 bf16 (4 VGPR)
typedef __attribute__((ext_vector_type(4))) float f32x4;    // MFMA acc frag

#define MFMA16(a, b, c) __builtin_amdgcn_mfma_f32_16x16x32_bf16((a), (b), (c), 0, 0, 0)

#define B_   4
#define C_   512
#define N_   4096
#define SCALE 0.044194173824159216f  // 1/sqrt(512)
#define ESHIFT 12.0f                 // uniform exp shift (overflow insurance)

__device__ __forceinline__ unsigned short f2bf(float f) {
    union { float f; unsigned int u; } v; v.f = f;
    unsigned int r = (v.u + 0x7fffu + ((v.u >> 16) & 1u)) >> 16;  // RNE
    return (unsigned short)r;
}
__device__ __forceinline__ float bf2f(unsigned short s) {
    union { unsigned int u; float f; } v; v.u = ((unsigned int)s) << 16;
    return v.f;
}

// async 16B global -> LDS (lane i lands at lds + i*16)
__device__ __forceinline__ void async16(const unsigned short* g, unsigned short* l) {
    __builtin_amdgcn_global_load_lds((const __attribute__((address_space(1))) unsigned int*)g,
                                     (__attribute__((address_space(3))) unsigned int*)l,
                                     16, 0, 0);
}

// ---------------- GroupNorm partial sums: 512 blocks (4 per group) ----------
// part[blk] = sum, part[512+blk] = sumsq  (blk = gid*4 + quarter)
__global__ __launch_bounds__(256) void gn_partial(const float* __restrict__ x,
                                                  float* __restrict__ part) {
    int blk = blockIdx.x;           // 0..511
    int gid = blk >> 2, qtr = blk & 3;
    const float4* base = (const float4*)(x + (size_t)gid * 65536) + qtr * 4096;
    float s = 0.f, ss = 0.f;
    for (int i = threadIdx.x; i < 4096; i += 256) {
        float4 v = base[i];
        s  += v.x + v.y + v.z + v.w;
        ss += v.x * v.x + v.y * v.y + v.z * v.z + v.w * v.w;
    }
    __shared__ float red[512];
    int t = threadIdx.x;
    red[t] = s; red[256 + t] = ss;
    __syncthreads();
    for (int st = 128; st > 0; st >>= 1) {
        if (t < st) { red[t] += red[t + st]; red[256 + t] += red[256 + t + st]; }
        __syncthreads();
    }
    if (t == 0) { part[blk] = red[0]; part[512 + blk] = red[256]; }
}

// ------------- GroupNorm apply + transpose -> Ht[b][n][c] bf16 --------------
__global__ __launch_bounds__(256) void gn_apply(const float* __restrict__ x,
                                                const float* __restrict__ gamma,
                                                const float* __restrict__ beta,
                                                const float* __restrict__ part,
                                                unsigned short* __restrict__ ht) {
    __shared__ float tile[64][65];
    __shared__ float mrs[4][2];
    int j0 = blockIdx.x * 64, c0 = blockIdx.y * 64, b = blockIdx.z;
    int t = threadIdx.x;
    if (t < 4) {  // finalize (mean, rstd) for the 4 groups this block touches
        int gid = b * 32 + (c0 >> 4) + t;
        float s = 0.f, ss = 0.f;
#pragma unroll
        for (int q = 0; q < 4; ++q) { s += part[gid * 4 + q]; ss += part[512 + gid * 4 + q]; }
        float mean = s * (1.f / 65536.f);
        float var  = ss * (1.f / 65536.f) - mean * mean;
        mrs[t][0] = mean;
        mrs[t][1] = rsqrtf(var + 1e-6f);
    }
    __syncthreads();
#pragma unroll
    for (int i = 0; i < 16; ++i) {
        int lid = i * 256 + t;
        int cl = lid >> 6, jl = lid & 63;
        int c = c0 + cl;
        float v = x[((size_t)b * C_ + c) * N_ + j0 + jl];
        tile[cl][jl] = (v - mrs[cl >> 4][0]) * mrs[cl >> 4][1] * gamma[c] + beta[c];
    }
    __syncthreads();
#pragma unroll
    for (int i = 0; i < 16; ++i) {
        int lid = i * 256 + t;
        int jl = lid >> 6, cl = lid & 63;
        ht[((size_t)b * N_ + j0 + jl) * C_ + c0 + cl] = f2bf(tile[cl][jl]);
    }
}

// ------------- convert the 4 weight matrices to bf16 ------------------------
__global__ __launch_bounds__(256) void wconv(const float* __restrict__ wq,
                                             const float* __restrict__ wk,
                                             const float* __restrict__ wv,
                                             const float* __restrict__ wo,
                                             unsigned short* __restrict__ dst) {
    size_t i = (size_t)blockIdx.x * 256 + threadIdx.x;  // 4*512*512 total
    int m = (int)(i >> 18);
    size_t off = i & 262143;
    const float* src = (m == 0) ? wq : (m == 1) ? wk : (m == 2) ? wv : wo;
    dst[i] = f2bf(src[off]);
}

// ------------- shared 128x128xK MFMA GEMM core, fragment-major LDS ----------
// LDS: 16 blocks of 1KB per tile. Block (grp 0..7, kkb 0..1) holds, at
// lane*16B, the chunk (row = grp*16 + (lane&15), kchunk = kkb*4 + (lane>>4)).
// Fragment read = lds_base + lane*16 -> stride-1, conflict-free.
template <typename EPI>
__device__ __forceinline__ void gemm_core(const unsigned short* __restrict__ Abase,
                                          const unsigned short* __restrict__ Bbase,
                                          size_t lda, size_t ldb, int K, EPI epi) {
    __shared__ unsigned short hl[128 * 64];
    __shared__ unsigned short wl[128 * 64];
    int t = threadIdx.x;
    int wv = t >> 6, lane = t & 63, l15 = lane & 15, quad = lane >> 4;
    int wm = wv & 1, wn = wv >> 1;
    int srow = lane & 15;                 // staging: row within 16-row group
    int scol = (lane >> 4) * 8;           // staging: k-chunk base (shorts)
    f32x4 acc[4][4] = {};
    for (int k0 = 0; k0 < K; k0 += 64) {
        __syncthreads();  // prior compute done before overwrite
#pragma unroll
        for (int i = 0; i < 4; ++i) {
            int seg = wv * 4 + i;                 // 16 segs x 1KB per tile
            int grp = seg >> 1, kkb = seg & 1;
            int row = grp * 16 + srow;
            int col = k0 + kkb * 32 + scol;
            async16(&Abase[(size_t)row * lda + col], &hl[seg * 512]);
            async16(&Bbase[(size_t)row * ldb + col], &wl[seg * 512]);
        }
        __builtin_amdgcn_s_waitcnt(0x3F70);       // vmcnt(0)
        __syncthreads();
#pragma unroll
        for (int kk = 0; kk < 2; ++kk) {
            bf16x8 af[4], bfr[4];
#pragma unroll
            for (int mi = 0; mi < 4; ++mi)
                af[mi] = *(const bf16x8*)&hl[(((wm * 4 + mi) << 1) + kk) * 512 + lane * 8];
#pragma unroll
            for (int ni = 0; ni < 4; ++ni)
                bfr[ni] = *(const bf16x8*)&wl[(((wn * 4 + ni) << 1) + kk) * 512 + lane * 8];
#pragma unroll
            for (int mi = 0; mi < 4; ++mi)
#pragma unroll
                for (int ni = 0; ni < 4; ++ni)
                    acc[mi][ni] = MFMA16(af[mi], bfr[ni], acc[mi][ni]);
        }
    }
    epi(acc, wm, wn, l15, quad);
}

// ------------- fused QKV projection: grid (32, 12, 4) -----------------------
__global__ __launch_bounds__(256) void gemm_qkv(const unsigned short* __restrict__ Ht,
                                                const unsigned short* __restrict__ Wb,
                                                const float* __restrict__ bq,
                                                const float* __restrict__ bk,
                                                const float* __restrict__ bv,
                                                unsigned short* __restrict__ Qt,
                                                unsigned short* __restrict__ Kt,
                                                unsigned short* __restrict__ Vg) {
    int b = blockIdx.z, j0 = blockIdx.x * 128;
    int ct = blockIdx.y;                 // 0..11
    int slab = ct >> 2, co0 = (ct & 3) * 128;
    const unsigned short* A = Ht + ((size_t)b * N_ + j0) * C_;
    const unsigned short* B = Wb + (size_t)slab * C_ * C_ + (size_t)co0 * C_;
    const float* bias = (slab == 0) ? bq : (slab == 1) ? bk : bv;
    unsigned short* outqk = (slab == 0) ? Qt : Kt;
    gemm_core(A, B, C_, C_, C_,
        [&](f32x4 (&acc)[4][4], int wm, int wn, int l15, int quad) {
        if (slab < 2) {
#pragma unroll
            for (int mi = 0; mi < 4; ++mi)
#pragma unroll
                for (int ni = 0; ni < 4; ++ni)
#pragma unroll
                    for (int r = 0; r < 4; ++r) {
                        int mrow = wm * 64 + mi * 16 + quad * 4 + r;
                        int ncol = wn * 64 + ni * 16 + l15;
                        outqk[((size_t)b * N_ + j0 + mrow) * C_ + co0 + ncol] =
                            f2bf(acc[mi][ni][r] + bias[co0 + ncol]);
                    }
        } else {
#pragma unroll
            for (int mi = 0; mi < 4; ++mi)
#pragma unroll
                for (int ni = 0; ni < 4; ++ni) {
                    int ncol = wn * 64 + ni * 16 + l15;
                    float bb = bias[co0 + ncol];
                    ushort4 pk;
                    pk.x = f2bf(acc[mi][ni][0] + bb);
                    pk.y = f2bf(acc[mi][ni][1] + bb);
                    pk.z = f2bf(acc[mi][ni][2] + bb);
                    pk.w = f2bf(acc[mi][ni][3] + bb);
                    int jb = j0 + wm * 64 + mi * 16 + quad * 4;
                    *(ushort4*)&Vg[((size_t)b * C_ + co0 + ncol) * N_ + jb] = pk;
                }
        }
    });
}

// ------------- GEMM1: P = exp(Q K^T * scale - 12), rowsum partials ----------
// grid (32, 32, 4).  psum layout: [wn*32+ktile][b*4096+q] f32 (64 x 16384).
__global__ __launch_bounds__(256) void gemm_qk_exp(const unsigned short* __restrict__ Qt,
                                                   const unsigned short* __restrict__ Kt,
                                                   unsigned short* __restrict__ P,
                                                   float* __restrict__ psum) {
    int b = blockIdx.z, j0 = blockIdx.x * 128, ktile = blockIdx.y;
    int kc0 = ktile * 128;
    const unsigned short* A = Qt + ((size_t)b * N_ + j0) * C_;
    const unsigned short* B = Kt + ((size_t)b * N_ + kc0) * C_;
    gemm_core(A, B, C_, C_, C_,
        [&](f32x4 (&acc)[4][4], int wm, int wn, int l15, int quad) {
        float rs[4][4];
#pragma unroll
        for (int mi = 0; mi < 4; ++mi)
#pragma unroll
            for (int r = 0; r < 4; ++r) rs[mi][r] = 0.f;
#pragma unroll
        for (int mi = 0; mi < 4; ++mi)
#pragma unroll
            for (int ni = 0; ni < 4; ++ni)
#pragma unroll
                for (int r = 0; r < 4; ++r) {
                    int mrow = wm * 64 + mi * 16 + quad * 4 + r;
                    int ncol = wn * 64 + ni * 16 + l15;
                    float p = __expf(acc[mi][ni][r] * SCALE - ESHIFT);
                    rs[mi][r] += p;
                    P[((size_t)b * N_ + j0 + mrow) * N_ + kc0 + ncol] = f2bf(p);
                }
#pragma unroll
        for (int mi = 0; mi < 4; ++mi)
#pragma unroll
            for (int r = 0; r < 4; ++r) {
                float v = rs[mi][r];
                v += __shfl_xor(v, 1);
                v += __shfl_xor(v, 2);
                v += __shfl_xor(v, 4);
                v += __shfl_xor(v, 8);
                if (l15 == 0)
                    psum[(size_t)(wn * 32 + ktile) * 16384 +
                         (size_t)b * N_ + j0 + wm * 64 + mi * 16 + quad * 4 + r] = v;
            }
    });
}

// ------------- GEMM2: O = (P V) / l -> AObf[b][n][c] bf16 -------------------
// flat grid 512, XCD-grouped: the 4 c-tiles sharing a P row-tile colocate.
__global__ __launch_bounds__(256) void gemm_pv(const unsigned short* __restrict__ P,
                                               const unsigned short* __restrict__ Vg,
                                               const float* __restrict__ psum,
                                               unsigned short* __restrict__ ao) {
    __shared__ float linv[128];
    int flat = blockIdx.x;
    int xcd = flat & 7, rr = flat >> 3;
    int ct = rr & 3, g = (rr >> 2) * 8 + xcd;   // g in [0,128)
    int b = g & 3, qtile = g >> 2;
    int j0 = qtile * 128, co0 = ct * 128;
    int t = threadIdx.x;
    if (t < 128) {
        size_t q = (size_t)b * N_ + j0 + t;
        float s = 0.f;
#pragma unroll
        for (int i = 0; i < 64; ++i) s += psum[(size_t)i * 16384 + q];
        linv[t] = 1.f / s;
    }
    const unsigned short* A = P + ((size_t)b * N_ + j0) * N_;
    const unsigned short* B = Vg + ((size_t)b * C_ + co0) * N_;
    gemm_core(A, B, N_, N_, N_,
        [&](f32x4 (&acc)[4][4], int wm, int wn, int l15, int quad) {
#pragma unroll
        for (int mi = 0; mi < 4; ++mi)
#pragma unroll
            for (int ni = 0; ni < 4; ++ni)
#pragma unroll
                for (int r = 0; r < 4; ++r) {
                    int mrow = wm * 64 + mi * 16 + quad * 4 + r;
                    int ncol = wn * 64 + ni * 16 + l15;
                    ao[((size_t)b * N_ + j0 + mrow) * C_ + co0 + ncol] =
                        f2bf(acc[mi][ni][r] * linv[mrow]);
                }
    });
}

// ------------- final projection + residual: grid (32, 4, 4) -----------------
__global__ __launch_bounds__(256) void gemm_resid(const unsigned short* __restrict__ AObf,
                                                  const unsigned short* __restrict__ Wo,
                                                  const float* __restrict__ bo,
                                                  const float* __restrict__ xres,
                                                  float* __restrict__ out) {
    int b = blockIdx.z, j0 = blockIdx.x * 128, co0 = blockIdx.y * 128;
    const unsigned short* A = AObf + ((size_t)b * N_ + j0) * C_;
    const unsigned short* B = Wo + (size_t)co0 * C_;
    gemm_core(A, B, C_, C_, C_,
        [&](f32x4 (&acc)[4][4], int wm, int wn, int l15, int quad) {
#pragma unroll
        for (int mi = 0; mi < 4; ++mi)
#pragma unroll
            for (int ni = 0; ni < 4; ++ni) {
                int ncol = wn * 64 + ni * 16 + l15;
                int jb = j0 + wm * 64 + mi * 16 + quad * 4;
                size_t o = ((size_t)b * C_ + co0 + ncol) * N_ + jb;
                float bb = bo[co0 + ncol];
                float4 xr = *(const float4*)&xres[o];
                float4 ov;
                ov.x = acc[mi][ni][0] + bb + xr.x;
                ov.y = acc[mi][ni][1] + bb + xr.y;
                ov.z = acc[mi][ni][2] + bb + xr.z;
                ov.w = acc[mi][ni][3] + bb + xr.w;
                *(float4*)&out[o] = ov;
            }
    });
}

// ------------- FALLBACK: R4 flash attention (if ws too small) ---------------
__global__ __launch_bounds__(256, 1) void flash_attn(const unsigned short* __restrict__ Qt,
                                                     const unsigned short* __restrict__ Kt,
                                                     const unsigned short* __restrict__ Vg,
                                                     unsigned short* __restrict__ part,
                                                     float* __restrict__ lbuf,
                                                     int nsplit) {
    extern __shared__ unsigned short smem[];
    unsigned short* Kl = smem;
    unsigned short* Vl = smem + 32768;
    unsigned short* Pl = smem + 65536;

    int flat = blockIdx.x;
    int qblk, b, s;
    if (nsplit == 2) { s = flat & 1; b = (flat >> 1) & 3; qblk = flat >> 3; }
    else             { s = 0;        b = flat & 3;        qblk = flat >> 2; }
    int q0 = qblk * 128;
    int t = threadIdx.x, w = t >> 6, lane = t & 63, l15 = lane & 15, quad = lane >> 4;
    int klen = N_ / nsplit, kbeg = s * klen, nkt = klen / 32;
    int xr = l15 & 7;

    const unsigned short* Kbase = Kt + (size_t)b * N_ * C_;
    const unsigned short* Vbase = Vg + (size_t)b * C_ * N_;

    bf16x8 qa[2][16];
#pragma unroll
    for (int u = 0; u < 2; ++u) {
        const unsigned short* qb =
            Qt + ((size_t)b * N_ + q0 + w * 32 + u * 16 + l15) * C_ + quad * 8;
#pragma unroll
        for (int ck = 0; ck < 16; ++ck) qa[u][ck] = *(const bf16x8*)(qb + ck * 32);
    }

    f32x4 o[2][32] = {};
    float lrow[2][4] = {};

    {
        int k0 = kbeg;
#pragma unroll
        for (int i = 0; i < 8; ++i) {
            int r = w * 8 + i;
            async16(Kbase + (size_t)(k0 + r) * C_ + ((lane ^ (r & 7)) * 8), Kl + r * 512);
        }
#pragma unroll
        for (int i = 0; i < 8; ++i) {
            int idx = w * 8 + i, kc = idx >> 3, cb = idx & 7;
            async16(Vbase + (size_t)(cb * 64 + lane) * N_ + k0 + kc * 8,
                    Vl + (kc * 512 + cb * 64) * 8);
        }
    }

    for (int kt = 0; kt < nkt; ++kt) {
        int cur = kt & 1, nxt = cur ^ 1;
        __builtin_amdgcn_s_waitcnt(0x3F70);
        __syncthreads();
        if (kt + 1 < nkt) {
            int k0 = kbeg + (kt + 1) * 32;
#pragma unroll
            for (int i = 0; i < 8; ++i) {
                int r = w * 8 + i;
                async16(Kbase + (size_t)(k0 + r) * C_ + ((lane ^ (r & 7)) * 8),
                        Kl + nxt * 16384 + r * 512);
            }
#pragma unroll
            for (int i = 0; i < 8; ++i) {
                int idx = w * 8 + i, kc = idx >> 3, cb = idx & 7;
                async16(Vbase + (size_t)(cb * 64 + lane) * N_ + k0 + kc * 8,
                        Vl + nxt * 16384 + (kc * 512 + cb * 64) * 8);
            }
        }
        const unsigned short* Kc = Kl + cur * 16384;
        f32x4 s00 = {}, s01 = {}, s10 = {}, s11 = {};
#pragma unroll
        for (int ck = 0; ck < 16; ++ck) {
            int slot = (ck * 4 + quad) ^ xr;
            bf16x8 b0 = *(const bf16x8*)&Kc[l15 * 512 + slot * 8];
            bf16x8 b1 = *(const bf16x8*)&Kc[(16 + l15) * 512 + slot * 8];
            s00 = MFMA16(qa[0][ck], b0, s00);
            s10 = MFMA16(qa[1][ck], b0, s10);
            s01 = MFMA16(qa[0][ck], b1, s01);
            s11 = MFMA16(qa[1][ck], b1, s11);
        }
        unsigned short* pb = &Pl[w * 1152];
#pragma unroll
        for (int r = 0; r < 4; ++r) {
            float p00 = __expf(s00[r] * SCALE - ESHIFT);
            float p01 = __expf(s01[r] * SCALE - ESHIFT);
            float p10 = __expf(s10[r] * SCALE - ESHIFT);
            float p11 = __expf(s11[r] * SCALE - ESHIFT);
            lrow[0][r] += p00 + p01;
            lrow[1][r] += p10 + p11;
            int row0 = (quad * 4 + r) * 36;
            int row1 = (16 + quad * 4 + r) * 36;
            pb[row0 + l15]      = f2bf(p00);
            pb[row0 + 16 + l15] = f2bf(p01);
            pb[row1 + l15]      = f2bf(p10);
            pb[row1 + 16 + l15] = f2bf(p11);
        }
        __builtin_amdgcn_s_waitcnt(0xC07F);
        bf16x8 pa0 = *(const bf16x8*)&Pl[w * 1152 + l15 * 36 + quad * 8];
        bf16x8 pa1 = *(const bf16x8*)&Pl[w * 1152 + (16 + l15) * 36 + quad * 8];
        const unsigned short* Vc = Vl + cur * 16384;
#pragma unroll
        for (int cf = 0; cf < 32; ++cf) {
            bf16x8 vb = *(const bf16x8*)&Vc[(quad * 512 + cf * 16 + l15) * 8];
            o[0][cf] = MFMA16(pa0, vb, o[0][cf]);
            o[1][cf] = MFMA16(pa1, vb, o[1][cf]);
        }
    }
#pragma unroll
    for (int u = 0; u < 2; ++u)
#pragma unroll
        for (int r = 0; r < 4; ++r) {
            float l = lrow[u][r];
            l += __shfl_xor(l, 1);
            l += __shfl_xor(l, 2);
            l += __shfl_xor(l, 4);
            l += __shfl_xor(l, 8);
            lrow[u][r] = l;
        }
    size_t pbase = (size_t)(s * B_ + b) * N_;
#pragma unroll
    for (int u = 0; u < 2; ++u)
#pragma unroll
        for (int cf = 0; cf < 32; ++cf)
#pragma unroll
            for (int r = 0; r < 4; ++r) {
                int q = q0 + w * 32 + u * 16 + quad * 4 + r;
                part[(pbase + q) * C_ + cf * 16 + l15] = f2bf(o[u][cf][r]);
            }
    if (l15 == 0) {
#pragma unroll
        for (int u = 0; u < 2; ++u)
#pragma unroll
            for (int r = 0; r < 4; ++r) {
                int q = q0 + w * 32 + u * 16 + quad * 4 + r;
                lbuf[pbase + q] = lrow[u][r];
            }
    }
}

__global__ __launch_bounds__(256) void attn_combine(const unsigned short* __restrict__ part,
                                                    const float* __restrict__ lbuf,
                                                    unsigned short* __restrict__ ao,
                                                    int nsplit) {
    size_t idx = (size_t)blockIdx.x * 256 + threadIdx.x;
    int cu = (int)(idx & 63);
    size_t row = idx >> 6;
    float l = lbuf[row];
    union { uint4 v; unsigned short u[8]; } p1, p2, outv;
    p1.v = *(const uint4*)&part[row * C_ + cu * 8];
    if (nsplit == 2) {
        l += lbuf[(size_t)B_ * N_ + row];
        p2.v = *(const uint4*)&part[((size_t)B_ * N_ + row) * C_ + cu * 8];
    } else {
        p2.v = make_uint4(0, 0, 0, 0);
    }
    float inv = 1.f / l;
#pragma unroll
    for (int j = 0; j < 8; ++j)
        outv.u[j] = f2bf((bf2f(p1.u[j]) + bf2f(p2.u[j])) * inv);
    *(uint4*)&ao[row * C_ + cu * 8] = outv.v;
}

// ---------------------------------------------------------------------------
extern "C" void kernel_launch(void* const* d_in, const int* in_sizes, int n_in,
                              void* d_out, int out_size, void* d_ws, size_t ws_size,
                              hipStream_t stream) {
    const float* x   = (const float*)d_in[0];
    const float* gam = (const float*)d_in[1];
    const float* bet = (const float*)d_in[2];
    const float* wq  = (const float*)d_in[3];
    const float* bq  = (const float*)d_in[4];
    const float* wk  = (const float*)d_in[5];
    const float* bk  = (const float*)d_in[6];
    const float* wv  = (const float*)d_in[7];
    const float* bv  = (const float*)d_in[8];
    const float* wo  = (const float*)d_in[9];
    const float* bo  = (const float*)d_in[10];
    float* out = (float*)d_out;

    char* ws = (char*)d_ws;
    const size_t SZH = (size_t)B_ * N_ * C_ * 2;          // 16 MiB bf16 tensor
    const size_t OFF_HT = 4096;                           // after 1024-float part buf
    const size_t OFF_QT = OFF_HT + SZH;
    const size_t OFF_KT = OFF_QT + SZH;
    const size_t OFF_VG = OFF_KT + SZH;
    const size_t OFF_WB = OFF_VG + SZH;
    const size_t OFF_X  = OFF_WB + 2097152;               // 69,210,112
    float*          part0 = (float*)ws;                   // gn partial sums
    unsigned short* Ht    = (unsigned short*)(ws + OFF_HT);
    unsigned short* Qt    = (unsigned short*)(ws + OFF_QT);
    unsigned short* Kt    = (unsigned short*)(ws + OFF_KT);
    unsigned short* Vg    = (unsigned short*)(ws + OFF_VG);
    unsigned short* Wb    = (unsigned short*)(ws + OFF_WB);
    unsigned short* AObf  = Ht;  // Ht dead after projections

    // Path A: materialized-P two-GEMM attention.
    const size_t SZPSUM = 64ull * 16384 * 4;              // 4 MiB
    const size_t SZP    = (size_t)B_ * N_ * N_ * 2;       // 128 MiB
    float*          psum = (float*)(ws + OFF_X);
    unsigned short* P    = (unsigned short*)(ws + OFF_X + SZPSUM);
    size_t needA = OFF_X + SZPSUM + SZP;

    // Path B (fallback): R4 flash.
    float*          lbuf = (float*)(ws + OFF_X);
    unsigned short* partb = (unsigned short*)(ws + OFF_X + 262144);
    size_t needB2 = OFF_X + 262144 + 2 * SZH;

    gn_partial<<<512, 256, 0, stream>>>(x, part0);
    gn_apply<<<dim3(64, 8, B_), 256, 0, stream>>>(x, gam, bet, part0, Ht);
    wconv<<<4096, 256, 0, stream>>>(wq, wk, wv, wo, Wb);
    gemm_qkv<<<dim3(32, 12, B_), 256, 0, stream>>>(Ht, Wb, bq, bk, bv, Qt, Kt, Vg);

    if (ws_size >= needA) {
        gemm_qk_exp<<<dim3(32, 32, B_), 256, 0, stream>>>(Qt, Kt, P, psum);
        gemm_pv<<<512, 256, 0, stream>>>(P, Vg, psum, AObf);
    } else {
        int nsplit = (ws_size >= needB2) ? 2 : 1;
        const int FLASH_LDS = 140288;
        (void)hipFuncSetAttribute((const void*)flash_attn,
                                  hipFuncAttributeMaxDynamicSharedMemorySize, FLASH_LDS);
        flash_attn<<<dim3(32 * B_ * nsplit), 256, FLASH_LDS, stream>>>(Qt, Kt, Vg, partb, lbuf, nsplit);
        attn_combine<<<4096, 256, 0, stream>>>(partb, lbuf, AObf, nsplit);
    }
    gemm_resid<<<dim3(32, 4, B_), 256, 0, stream>>>(AObf, Wb + 786432, bo, x, out);
}

// Round 7
// 360.373 us; speedup vs baseline: 1.3252x; 1.3252x over previous
//
#include <hip/hip_runtime.h>

// ---------------------------------------------------------------------------
// AttnBlock: GroupNorm -> q,k,v 1x1 conv -> softmax(QK^T/sqrt(c)) V -> out
// conv -> residual.  b=4, c=512, h=w=64 (n=4096), 32 groups.
// R7: gemm_core = R5 coalesced staging + XOR bank swizzle (conflict-free,
//     verified concept R6) + double-buffered LDS with one barrier/iter and
//     loads issued post-barrier (prefetch in flight through whole compute
//     phase -> vmcnt(0) nearly free).
// ---------------------------------------------------------------------------

typedef __attribute__((ext_vector_type(8))) short bf16x8;   // 8 bf16 (4 VGPR)
typedef __attribute__((ext_vector_type(4))) float f32x4;    // MFMA acc frag

#define MFMA16(a, b, c) __builtin_amdgcn_mfma_f32_16x16x32_bf16((a), (b), (c), 0, 0, 0)

#define B_   4
#define C_   512
#define N_   4096
#define SCALE 0.044194173824159216f  // 1/sqrt(512)
#define ESHIFT 12.0f                 // uniform exp shift (overflow insurance)

__device__ __forceinline__ unsigned short f2bf(float f) {
    union { float f; unsigned int u; } v; v.f = f;
    unsigned int r = (v.u + 0x7fffu + ((v.u >> 16) & 1u)) >> 16;  // RNE
    return (unsigned short)r;
}
__device__ __forceinline__ float bf2f(unsigned short s) {
    union { unsigned int u; float f; } v; v.u = ((unsigned int)s) << 16;
    return v.f;
}

// async 16B global -> LDS (lane i lands at lds + i*16)
__device__ __forceinline__ void async16(const unsigned short* g, unsigned short* l) {
    __builtin_amdgcn_global_load_lds((const __attribute__((address_space(1))) unsigned int*)g,
                                     (__attribute__((address_space(3))) unsigned int*)l,
                                     16, 0, 0);
}

// ---------------- GroupNorm partial sums: 512 blocks (4 per group) ----------
__global__ __launch_bounds__(256) void gn_partial(const float* __restrict__ x,
                                                  float* __restrict__ part) {
    int blk = blockIdx.x;           // 0..511
    int gid = blk >> 2, qtr = blk & 3;
    const float4* base = (const float4*)(x + (size_t)gid * 65536) + qtr * 4096;
    float s = 0.f, ss = 0.f;
    for (int i = threadIdx.x; i < 4096; i += 256) {
        float4 v = base[i];
        s  += v.x + v.y + v.z + v.w;
        ss += v.x * v.x + v.y * v.y + v.z * v.z + v.w * v.w;
    }
    __shared__ float red[512];
    int t = threadIdx.x;
    red[t] = s; red[256 + t] = ss;
    __syncthreads();
    for (int st = 128; st > 0; st >>= 1) {
        if (t < st) { red[t] += red[t + st]; red[256 + t] += red[256 + t + st]; }
        __syncthreads();
    }
    if (t == 0) { part[blk] = red[0]; part[512 + blk] = red[256]; }
}

// ------------- GroupNorm apply + transpose -> Ht[b][n][c] bf16 --------------
__global__ __launch_bounds__(256) void gn_apply(const float* __restrict__ x,
                                                const float* __restrict__ gamma,
                                                const float* __restrict__ beta,
                                                const float* __restrict__ part,
                                                unsigned short* __restrict__ ht) {
    __shared__ float tile[64][65];
    __shared__ float mrs[4][2];
    int j0 = blockIdx.x * 64, c0 = blockIdx.y * 64, b = blockIdx.z;
    int t = threadIdx.x;
    if (t < 4) {
        int gid = b * 32 + (c0 >> 4) + t;
        float s = 0.f, ss = 0.f;
#pragma unroll
        for (int q = 0; q < 4; ++q) { s += part[gid * 4 + q]; ss += part[512 + gid * 4 + q]; }
        float mean = s * (1.f / 65536.f);
        float var  = ss * (1.f / 65536.f) - mean * mean;
        mrs[t][0] = mean;
        mrs[t][1] = rsqrtf(var + 1e-6f);
    }
    __syncthreads();
#pragma unroll
    for (int i = 0; i < 16; ++i) {
        int lid = i * 256 + t;
        int cl = lid >> 6, jl = lid & 63;
        int c = c0 + cl;
        float v = x[((size_t)b * C_ + c) * N_ + j0 + jl];
        tile[cl][jl] = (v - mrs[cl >> 4][0]) * mrs[cl >> 4][1] * gamma[c] + beta[c];
    }
    __syncthreads();
#pragma unroll
    for (int i = 0; i < 16; ++i) {
        int lid = i * 256 + t;
        int jl = lid >> 6, cl = lid & 63;
        ht[((size_t)b * N_ + j0 + jl) * C_ + c0 + cl] = f2bf(tile[cl][jl]);
    }
}

// ------------- convert the 4 weight matrices to bf16 ------------------------
__global__ __launch_bounds__(256) void wconv(const float* __restrict__ wq,
                                             const float* __restrict__ wk,
                                             const float* __restrict__ wv,
                                             const float* __restrict__ wo,
                                             unsigned short* __restrict__ dst) {
    size_t i = (size_t)blockIdx.x * 256 + threadIdx.x;  // 4*512*512 total
    int m = (int)(i >> 18);
    size_t off = i & 262143;
    const float* src = (m == 0) ? wq : (m == 1) ? wk : (m == 2) ? wv : wo;
    dst[i] = f2bf(src[off]);
}

// ------------- 128x128xK MFMA GEMM core: dbuf + XOR-swizzled LDS ------------
// Staging (per tile): 16 segs x 8 rows x 128B; lane covers row (lane>>3),
// chunk (lane&7)^(lane>>3) -> slot s of row r holds chunk s^(r&7).
// Global: each 8-lane group reads one contiguous 128B row segment (coalesced).
// Fragment read: row*64 + ((kk*4+quad)^(l15&7))*8 -> every 8-lane group hits
// 8 distinct 4-bank groups: conflict-free.
// Pipeline: vmcnt(0); barrier; issue tile k+1 -> buf^1; compute buf[cur].
template <typename EPI>
__device__ __forceinline__ void gemm_core(const unsigned short* __restrict__ Abase,
                                          const unsigned short* __restrict__ Bbase,
                                          size_t lda, size_t ldb, int K, EPI epi) {
    __shared__ unsigned short hl[2][128 * 64];
    __shared__ unsigned short wl[2][128 * 64];
    int t = threadIdx.x;
    int wv = t >> 6, lane = t & 63, l15 = lane & 15, quad = lane >> 4;
    int wm = wv & 1, wn = wv >> 1;
    int srow = lane >> 3;                    // row within 8-row seg
    int sch  = ((lane & 7) ^ srow) * 8;      // XOR-swizzled chunk offset
    int xr = l15 & 7;
    f32x4 acc[4][4] = {};
    // prologue: stage tile 0 into buf 0
#pragma unroll
    for (int i = 0; i < 4; ++i) {
        int seg = wv * 4 + i;
        size_t row = seg * 8 + srow;
        async16(&Abase[row * lda + sch], &hl[0][seg * 512]);
        async16(&Bbase[row * ldb + sch], &wl[0][seg * 512]);
    }
    int nk = K >> 6;
    for (int k = 0; k < nk; ++k) {
        int cur = k & 1;
        __builtin_amdgcn_s_waitcnt(0x3F70);  // vmcnt(0): tile k staged (in flight
        __syncthreads();                     // through all of compute k-1)
        if (k + 1 < nk) {                    // prefetch k+1 (post-barrier: buf free)
            int k0 = (k + 1) << 6;
#pragma unroll
            for (int i = 0; i < 4; ++i) {
                int seg = wv * 4 + i;
                size_t row = seg * 8 + srow;
                async16(&Abase[row * lda + k0 + sch], &hl[cur ^ 1][seg * 512]);
                async16(&Bbase[row * ldb + k0 + sch], &wl[cur ^ 1][seg * 512]);
            }
        }
#pragma unroll
        for (int kk = 0; kk < 2; ++kk) {
            int sl = (((kk << 2) + quad) ^ xr) * 8;
            bf16x8 af[4], bfr[4];
#pragma unroll
            for (int mi = 0; mi < 4; ++mi)
                af[mi] = *(const bf16x8*)&hl[cur][(wm * 64 + mi * 16 + l15) * 64 + sl];
#pragma unroll
            for (int ni = 0; ni < 4; ++ni)
                bfr[ni] = *(const bf16x8*)&wl[cur][(wn * 64 + ni * 16 + l15) * 64 + sl];
#pragma unroll
            for (int mi = 0; mi < 4; ++mi)
#pragma unroll
                for (int ni = 0; ni < 4; ++ni)
                    acc[mi][ni] = MFMA16(af[mi], bfr[ni], acc[mi][ni]);
        }
    }
    epi(acc, wm, wn, l15, quad);
}

// ------------- fused QKV projection: grid (32, 12, 4) -----------------------
__global__ __launch_bounds__(256) void gemm_qkv(const unsigned short* __restrict__ Ht,
                                                const unsigned short* __restrict__ Wb,
                                                const float* __restrict__ bq,
                                                const float* __restrict__ bk,
                                                const float* __restrict__ bv,
                                                unsigned short* __restrict__ Qt,
                                                unsigned short* __restrict__ Kt,
                                                unsigned short* __restrict__ Vg) {
    int b = blockIdx.z, j0 = blockIdx.x * 128;
    int ct = blockIdx.y;                 // 0..11
    int slab = ct >> 2, co0 = (ct & 3) * 128;
    const unsigned short* A = Ht + ((size_t)b * N_ + j0) * C_;
    const unsigned short* B = Wb + (size_t)slab * C_ * C_ + (size_t)co0 * C_;
    const float* bias = (slab == 0) ? bq : (slab == 1) ? bk : bv;
    unsigned short* outqk = (slab == 0) ? Qt : Kt;
    gemm_core(A, B, C_, C_, C_,
        [&](f32x4 (&acc)[4][4], int wm, int wn, int l15, int quad) {
        if (slab < 2) {
#pragma unroll
            for (int mi = 0; mi < 4; ++mi)
#pragma unroll
                for (int ni = 0; ni < 4; ++ni)
#pragma unroll
                    for (int r = 0; r < 4; ++r) {
                        int mrow = wm * 64 + mi * 16 + quad * 4 + r;
                        int ncol = wn * 64 + ni * 16 + l15;
                        outqk[((size_t)b * N_ + j0 + mrow) * C_ + co0 + ncol] =
                            f2bf(acc[mi][ni][r] + bias[co0 + ncol]);
                    }
        } else {
#pragma unroll
            for (int mi = 0; mi < 4; ++mi)
#pragma unroll
                for (int ni = 0; ni < 4; ++ni) {
                    int ncol = wn * 64 + ni * 16 + l15;
                    float bb = bias[co0 + ncol];
                    ushort4 pk;
                    pk.x = f2bf(acc[mi][ni][0] + bb);
                    pk.y = f2bf(acc[mi][ni][1] + bb);
                    pk.z = f2bf(acc[mi][ni][2] + bb);
                    pk.w = f2bf(acc[mi][ni][3] + bb);
                    int jb = j0 + wm * 64 + mi * 16 + quad * 4;
                    *(ushort4*)&Vg[((size_t)b * C_ + co0 + ncol) * N_ + jb] = pk;
                }
        }
    });
}

// ------------- GEMM1: P = exp(Q K^T * scale - 12), rowsum partials ----------
// grid (32, 32, 4).  psum layout: [wn*32+ktile][b*4096+q] f32 (64 x 16384).
__global__ __launch_bounds__(256) void gemm_qk_exp(const unsigned short* __restrict__ Qt,
                                                   const unsigned short* __restrict__ Kt,
                                                   unsigned short* __restrict__ P,
                                                   float* __restrict__ psum) {
    int b = blockIdx.z, j0 = blockIdx.x * 128, ktile = blockIdx.y;
    int kc0 = ktile * 128;
    const unsigned short* A = Qt + ((size_t)b * N_ + j0) * C_;
    const unsigned short* B = Kt + ((size_t)b * N_ + kc0) * C_;
    gemm_core(A, B, C_, C_, C_,
        [&](f32x4 (&acc)[4][4], int wm, int wn, int l15, int quad) {
        float rs[4][4];
#pragma unroll
        for (int mi = 0; mi < 4; ++mi)
#pragma unroll
            for (int r = 0; r < 4; ++r) rs[mi][r] = 0.f;
#pragma unroll
        for (int mi = 0; mi < 4; ++mi)
#pragma unroll
            for (int ni = 0; ni < 4; ++ni)
#pragma unroll
                for (int r = 0; r < 4; ++r) {
                    int mrow = wm * 64 + mi * 16 + quad * 4 + r;
                    int ncol = wn * 64 + ni * 16 + l15;
                    float p = __expf(acc[mi][ni][r] * SCALE - ESHIFT);
                    rs[mi][r] += p;
                    P[((size_t)b * N_ + j0 + mrow) * N_ + kc0 + ncol] = f2bf(p);
                }
#pragma unroll
        for (int mi = 0; mi < 4; ++mi)
#pragma unroll
            for (int r = 0; r < 4; ++r) {
                float v = rs[mi][r];
                v += __shfl_xor(v, 1);
                v += __shfl_xor(v, 2);
                v += __shfl_xor(v, 4);
                v += __shfl_xor(v, 8);
                if (l15 == 0)
                    psum[(size_t)(wn * 32 + ktile) * 16384 +
                         (size_t)b * N_ + j0 + wm * 64 + mi * 16 + quad * 4 + r] = v;
            }
    });
}

// ------------- GEMM2: O = (P V) / l -> AObf[b][n][c] bf16 -------------------
__global__ __launch_bounds__(256) void gemm_pv(const unsigned short* __restrict__ P,
                                               const unsigned short* __restrict__ Vg,
                                               const float* __restrict__ psum,
                                               unsigned short* __restrict__ ao) {
    __shared__ float linv[128];
    int flat = blockIdx.x;
    int xcd = flat & 7, rr = flat >> 3;
    int ct = rr & 3, g = (rr >> 2) * 8 + xcd;   // g in [0,128)
    int b = g & 3, qtile = g >> 2;
    int j0 = qtile * 128, co0 = ct * 128;
    int t = threadIdx.x;
    if (t < 128) {
        size_t q = (size_t)b * N_ + j0 + t;
        float s = 0.f;
#pragma unroll
        for (int i = 0; i < 64; ++i) s += psum[(size_t)i * 16384 + q];
        linv[t] = 1.f / s;
    }
    const unsigned short* A = P + ((size_t)b * N_ + j0) * N_;
    const unsigned short* B = Vg + ((size_t)b * C_ + co0) * N_;
    gemm_core(A, B, N_, N_, N_,
        [&](f32x4 (&acc)[4][4], int wm, int wn, int l15, int quad) {
#pragma unroll
        for (int mi = 0; mi < 4; ++mi)
#pragma unroll
            for (int ni = 0; ni < 4; ++ni)
#pragma unroll
                for (int r = 0; r < 4; ++r) {
                    int mrow = wm * 64 + mi * 16 + quad * 4 + r;
                    int ncol = wn * 64 + ni * 16 + l15;
                    ao[((size_t)b * N_ + j0 + mrow) * C_ + co0 + ncol] =
                        f2bf(acc[mi][ni][r] * linv[mrow]);
                }
    });
}

// ------------- final projection + residual: grid (32, 4, 4) -----------------
__global__ __launch_bounds__(256) void gemm_resid(const unsigned short* __restrict__ AObf,
                                                  const unsigned short* __restrict__ Wo,
                                                  const float* __restrict__ bo,
                                                  const float* __restrict__ xres,
                                                  float* __restrict__ out) {
    int b = blockIdx.z, j0 = blockIdx.x * 128, co0 = blockIdx.y * 128;
    const unsigned short* A = AObf + ((size_t)b * N_ + j0) * C_;
    const unsigned short* B = Wo + (size_t)co0 * C_;
    gemm_core(A, B, C_, C_, C_,
        [&](f32x4 (&acc)[4][4], int wm, int wn, int l15, int quad) {
#pragma unroll
        for (int mi = 0; mi < 4; ++mi)
#pragma unroll
            for (int ni = 0; ni < 4; ++ni) {
                int ncol = wn * 64 + ni * 16 + l15;
                int jb = j0 + wm * 64 + mi * 16 + quad * 4;
                size_t o = ((size_t)b * C_ + co0 + ncol) * N_ + jb;
                float bb = bo[co0 + ncol];
                float4 xr = *(const float4*)&xres[o];
                float4 ov;
                ov.x = acc[mi][ni][0] + bb + xr.x;
                ov.y = acc[mi][ni][1] + bb + xr.y;
                ov.z = acc[mi][ni][2] + bb + xr.z;
                ov.w = acc[mi][ni][3] + bb + xr.w;
                *(float4*)&out[o] = ov;
            }
    });
}

// ------------- FALLBACK: R4 flash attention (if ws too small) ---------------
__global__ __launch_bounds__(256, 1) void flash_attn(const unsigned short* __restrict__ Qt,
                                                     const unsigned short* __restrict__ Kt,
                                                     const unsigned short* __restrict__ Vg,
                                                     unsigned short* __restrict__ part,
                                                     float* __restrict__ lbuf,
                                                     int nsplit) {
    extern __shared__ unsigned short smem[];
    unsigned short* Kl = smem;
    unsigned short* Vl = smem + 32768;
    unsigned short* Pl = smem + 65536;

    int flat = blockIdx.x;
    int qblk, b, s;
    if (nsplit == 2) { s = flat & 1; b = (flat >> 1) & 3; qblk = flat >> 3; }
    else             { s = 0;        b = flat & 3;        qblk = flat >> 2; }
    int q0 = qblk * 128;
    int t = threadIdx.x, w = t >> 6, lane = t & 63, l15 = lane & 15, quad = lane >> 4;
    int klen = N_ / nsplit, kbeg = s * klen, nkt = klen / 32;
    int xr = l15 & 7;

    const unsigned short* Kbase = Kt + (size_t)b * N_ * C_;
    const unsigned short* Vbase = Vg + (size_t)b * C_ * N_;

    bf16x8 qa[2][16];
#pragma unroll
    for (int u = 0; u < 2; ++u) {
        const unsigned short* qb =
            Qt + ((size_t)b * N_ + q0 + w * 32 + u * 16 + l15) * C_ + quad * 8;
#pragma unroll
        for (int ck = 0; ck < 16; ++ck) qa[u][ck] = *(const bf16x8*)(qb + ck * 32);
    }

    f32x4 o[2][32] = {};
    float lrow[2][4] = {};

    {
        int k0 = kbeg;
#pragma unroll
        for (int i = 0; i < 8; ++i) {
            int r = w * 8 + i;
            async16(Kbase + (size_t)(k0 + r) * C_ + ((lane ^ (r & 7)) * 8), Kl + r * 512);
        }
#pragma unroll
        for (int i = 0; i < 8; ++i) {
            int idx = w * 8 + i, kc = idx >> 3, cb = idx & 7;
            async16(Vbase + (size_t)(cb * 64 + lane) * N_ + k0 + kc * 8,
                    Vl + (kc * 512 + cb * 64) * 8);
        }
    }

    for (int kt = 0; kt < nkt; ++kt) {
        int cur = kt & 1, nxt = cur ^ 1;
        __builtin_amdgcn_s_waitcnt(0x3F70);
        __syncthreads();
        if (kt + 1 < nkt) {
            int k0 = kbeg + (kt + 1) * 32;
#pragma unroll
            for (int i = 0; i < 8; ++i) {
                int r = w * 8 + i;
                async16(Kbase + (size_t)(k0 + r) * C_ + ((lane ^ (r & 7)) * 8),
                        Kl + nxt * 16384 + r * 512);
            }
#pragma unroll
            for (int i = 0; i < 8; ++i) {
                int idx = w * 8 + i, kc = idx >> 3, cb = idx & 7;
                async16(Vbase + (size_t)(cb * 64 + lane) * N_ + k0 + kc * 8,
                        Vl + nxt * 16384 + (kc * 512 + cb * 64) * 8);
            }
        }
        const unsigned short* Kc = Kl + cur * 16384;
        f32x4 s00 = {}, s01 = {}, s10 = {}, s11 = {};
#pragma unroll
        for (int ck = 0; ck < 16; ++ck) {
            int slot = (ck * 4 + quad) ^ xr;
            bf16x8 b0 = *(const bf16x8*)&Kc[l15 * 512 + slot * 8];
            bf16x8 b1 = *(const bf16x8*)&Kc[(16 + l15) * 512 + slot * 8];
            s00 = MFMA16(qa[0][ck], b0, s00);
            s10 = MFMA16(qa[1][ck], b0, s10);
            s01 = MFMA16(qa[0][ck], b1, s01);
            s11 = MFMA16(qa[1][ck], b1, s11);
        }
        unsigned short* pb = &Pl[w * 1152];
#pragma unroll
        for (int r = 0; r < 4; ++r) {
            float p00 = __expf(s00[r] * SCALE - ESHIFT);
            float p01 = __expf(s01[r] * SCALE - ESHIFT);
            float p10 = __expf(s10[r] * SCALE - ESHIFT);
            float p11 = __expf(s11[r] * SCALE - ESHIFT);
            lrow[0][r] += p00 + p01;
            lrow[1][r] += p10 + p11;
            int row0 = (quad * 4 + r) * 36;
            int row1 = (16 + quad * 4 + r) * 36;
            pb[row0 + l15]      = f2bf(p00);
            pb[row0 + 16 + l15] = f2bf(p01);
            pb[row1 + l15]      = f2bf(p10);
            pb[row1 + 16 + l15] = f2bf(p11);
        }
        __builtin_amdgcn_s_waitcnt(0xC07F);
        bf16x8 pa0 = *(const bf16x8*)&Pl[w * 1152 + l15 * 36 + quad * 8];
        bf16x8 pa1 = *(const bf16x8*)&Pl[w * 1152 + (16 + l15) * 36 + quad * 8];
        const unsigned short* Vc = Vl + cur * 16384;
#pragma unroll
        for (int cf = 0; cf < 32; ++cf) {
            bf16x8 vb = *(const bf16x8*)&Vc[(quad * 512 + cf * 16 + l15) * 8];
            o[0][cf] = MFMA16(pa0, vb, o[0][cf]);
            o[1][cf] = MFMA16(pa1, vb, o[1][cf]);
        }
    }
#pragma unroll
    for (int u = 0; u < 2; ++u)
#pragma unroll
        for (int r = 0; r < 4; ++r) {
            float l = lrow[u][r];
            l += __shfl_xor(l, 1);
            l += __shfl_xor(l, 2);
            l += __shfl_xor(l, 4);
            l += __shfl_xor(l, 8);
            lrow[u][r] = l;
        }
    size_t pbase = (size_t)(s * B_ + b) * N_;
#pragma unroll
    for (int u = 0; u < 2; ++u)
#pragma unroll
        for (int cf = 0; cf < 32; ++cf)
#pragma unroll
            for (int r = 0; r < 4; ++r) {
                int q = q0 + w * 32 + u * 16 + quad * 4 + r;
                part[(pbase + q) * C_ + cf * 16 + l15] = f2bf(o[u][cf][r]);
            }
    if (l15 == 0) {
#pragma unroll
        for (int u = 0; u < 2; ++u)
#pragma unroll
            for (int r = 0; r < 4; ++r) {
                int q = q0 + w * 32 + u * 16 + quad * 4 + r;
                lbuf[pbase + q] = lrow[u][r];
            }
    }
}

__global__ __launch_bounds__(256) void attn_combine(const unsigned short* __restrict__ part,
                                                    const float* __restrict__ lbuf,
                                                    unsigned short* __restrict__ ao,
                                                    int nsplit) {
    size_t idx = (size_t)blockIdx.x * 256 + threadIdx.x;
    int cu = (int)(idx & 63);
    size_t row = idx >> 6;
    float l = lbuf[row];
    union { uint4 v; unsigned short u[8]; } p1, p2, outv;
    p1.v = *(const uint4*)&part[row * C_ + cu * 8];
    if (nsplit == 2) {
        l += lbuf[(size_t)B_ * N_ + row];
        p2.v = *(const uint4*)&part[((size_t)B_ * N_ + row) * C_ + cu * 8];
    } else {
        p2.v = make_uint4(0, 0, 0, 0);
    }
    float inv = 1.f / l;
#pragma unroll
    for (int j = 0; j < 8; ++j)
        outv.u[j] = f2bf((bf2f(p1.u[j]) + bf2f(p2.u[j])) * inv);
    *(uint4*)&ao[row * C_ + cu * 8] = outv.v;
}

// ---------------------------------------------------------------------------
extern "C" void kernel_launch(void* const* d_in, const int* in_sizes, int n_in,
                              void* d_out, int out_size, void* d_ws, size_t ws_size,
                              hipStream_t stream) {
    const float* x   = (const float*)d_in[0];
    const float* gam = (const float*)d_in[1];
    const float* bet = (const float*)d_in[2];
    const float* wq  = (const float*)d_in[3];
    const float* bq  = (const float*)d_in[4];
    const float* wk  = (const float*)d_in[5];
    const float* bk  = (const float*)d_in[6];
    const float* wv  = (const float*)d_in[7];
    const float* bv  = (const float*)d_in[8];
    const float* wo  = (const float*)d_in[9];
    const float* bo  = (const float*)d_in[10];
    float* out = (float*)d_out;

    char* ws = (char*)d_ws;
    const size_t SZH = (size_t)B_ * N_ * C_ * 2;          // 16 MiB bf16 tensor
    const size_t OFF_HT = 4096;
    const size_t OFF_QT = OFF_HT + SZH;
    const size_t OFF_KT = OFF_QT + SZH;
    const size_t OFF_VG = OFF_KT + SZH;
    const size_t OFF_WB = OFF_VG + SZH;
    const size_t OFF_X  = OFF_WB + 2097152;               // 69,210,112
    float*          part0 = (float*)ws;                   // gn partial sums
    unsigned short* Ht    = (unsigned short*)(ws + OFF_HT);
    unsigned short* Qt    = (unsigned short*)(ws + OFF_QT);
    unsigned short* Kt    = (unsigned short*)(ws + OFF_KT);
    unsigned short* Vg    = (unsigned short*)(ws + OFF_VG);
    unsigned short* Wb    = (unsigned short*)(ws + OFF_WB);
    unsigned short* AObf  = Ht;  // Ht dead after projections

    // Path A: materialized-P two-GEMM attention.
    const size_t SZPSUM = 64ull * 16384 * 4;              // 4 MiB
    const size_t SZP    = (size_t)B_ * N_ * N_ * 2;       // 128 MiB
    float*          psum = (float*)(ws + OFF_X);
    unsigned short* P    = (unsigned short*)(ws + OFF_X + SZPSUM);
    size_t needA = OFF_X + SZPSUM + SZP;

    // Path B (fallback): R4 flash.
    float*          lbuf = (float*)(ws + OFF_X);
    unsigned short* partb = (unsigned short*)(ws + OFF_X + 262144);
    size_t needB2 = OFF_X + 262144 + 2 * SZH;

    gn_partial<<<512, 256, 0, stream>>>(x, part0);
    gn_apply<<<dim3(64, 8, B_), 256, 0, stream>>>(x, gam, bet, part0, Ht);
    wconv<<<4096, 256, 0, stream>>>(wq, wk, wv, wo, Wb);
    gemm_qkv<<<dim3(32, 12, B_), 256, 0, stream>>>(Ht, Wb, bq, bk, bv, Qt, Kt, Vg);

    if (ws_size >= needA) {
        gemm_qk_exp<<<dim3(32, 32, B_), 256, 0, stream>>>(Qt, Kt, P, psum);
        gemm_pv<<<512, 256, 0, stream>>>(P, Vg, psum, AObf);
    } else {
        int nsplit = (ws_size >= needB2) ? 2 : 1;
        const int FLASH_LDS = 140288;
        (void)hipFuncSetAttribute((const void*)flash_attn,
                                  hipFuncAttributeMaxDynamicSharedMemorySize, FLASH_LDS);
        flash_attn<<<dim3(32 * B_ * nsplit), 256, FLASH_LDS, stream>>>(Qt, Kt, Vg, partb, lbuf, nsplit);
        attn_combine<<<4096, 256, 0, stream>>>(partb, lbuf, AObf, nsplit);
    }
    gemm_resid<<<dim3(32, 4, B_), 256, 0, stream>>>(AObf, Wb + 786432, bo, x, out);
}